// Round 15
// baseline (425.923 us; speedup 1.0000x reference)
//
#include <hip/hip_runtime.h>
#include <hip/hip_bf16.h>

// Problem constants
#define PN 16384
#define PZ 100
#define PE 400
#define PM0 4000
#define PM1 2000
#define KP 128            // packed K: [0,100)=theta/topic, [100,104)=onehot/bias, rest 0
#define SEG1ROW 4096      // B2T row base of segment 1
#define MROWS 6144        // 4096 (seg0 pad) + 2048 (seg1 pad)

typedef __attribute__((ext_vector_type(8))) _Float16 half8v;
typedef __attribute__((ext_vector_type(4))) float floatx4;
typedef __attribute__((ext_vector_type(4))) unsigned int uint4v;

// ---------------------------------------------------------------------------
// zero-fill whole B2T (pads + k-slop deterministically zero)
// ---------------------------------------------------------------------------
__global__ __launch_bounds__(256) void fill_kernel(uint4v* __restrict__ p, int n16)
{
    int i = blockIdx.x * 256 + threadIdx.x;
    if (i < n16) p[i] = (uint4v){0u, 0u, 0u, 0u};
}

// ---------------------------------------------------------------------------
// topic v5 (unchanged): grid (96,5); block = 64 m x 20 z; thread = 1 m x 5 z.
// ---------------------------------------------------------------------------
__global__ __launch_bounds__(256) void topic_kernel(
    const float* __restrict__ alpha0, const float* __restrict__ alpha1,
    const float* __restrict__ beta, _Float16* __restrict__ b2t)
{
    __shared__ float sAl[64][101];   // 25.9 KB
    __shared__ float sBt[20][100];   // 8 KB

    const int seg = (blockIdx.x >= 64);
    const int tile = seg ? (blockIdx.x - 64) : blockIdx.x;
    const float* alpha = seg ? alpha1 : alpha0;
    const int Mse = seg ? PM1 : PM0;
    const int rowbase = (seg ? SEG1ROW : 0) + tile * 64;
    const int m0 = tile * 64;

    const int tid = threadIdx.x;
    const int ml = tid & 63;
    const int zt = tid >> 6;
    const int z0 = blockIdx.y * 20;

    float acc[5] = {0.f, 0.f, 0.f, 0.f, 0.f};

    for (int ec = 0; ec < 4; ++ec) {
        #pragma unroll
        for (int l = 0; l < 25; ++l) {
            int idx = tid + l * 256;
            int mr = idx / 100;
            int e  = idx - mr * 100;
            int mm = m0 + mr;
            sAl[mr][e] = (mm < Mse) ? alpha[(size_t)mm * PE + ec * 100 + e] : 0.f;
        }
        for (int idx = tid; idx < 2000; idx += 256) {
            int zr = idx / 100;
            int e  = idx - zr * 100;
            sBt[zr][e] = beta[(size_t)(z0 + zr) * PE + ec * 100 + e];
        }
        __syncthreads();

        #pragma unroll 2
        for (int e = 0; e < 100; ++e) {
            float a = sAl[ml][e];
            #pragma unroll
            for (int zi = 0; zi < 5; ++zi)
                acc[zi] = fmaf(sBt[zt * 5 + zi][e], a, acc[zi]);
        }
        __syncthreads();
    }

    int m = m0 + ml;
    if (m < Mse) {
        #pragma unroll
        for (int zi = 0; zi < 5; ++zi)
            b2t[(size_t)(rowbase + ml) * KP + (z0 + zt * 5 + zi)] = (_Float16)acc[zi];
    }
}

// ---------------------------------------------------------------------------
// bias cols k=100..103 of B2T (one thread per row)
// ---------------------------------------------------------------------------
__global__ __launch_bounds__(256) void bias_kernel(
    const float* __restrict__ bias0, const float* __restrict__ bias1,
    _Float16* __restrict__ b2t)
{
    int row = blockIdx.x * 256 + threadIdx.x;
    if (row >= MROWS) return;
    int seg = (row >= SEG1ROW);
    int m = row - (seg ? SEG1ROW : 0);
    int Mse = seg ? PM1 : PM0;
    const float* bias = seg ? bias1 : bias0;
    if (m < Mse) {
        #pragma unroll
        for (int d = 0; d < 4; ++d)
            b2t[(size_t)row * KP + 100 + d] = (_Float16)bias[(size_t)d * Mse + m];
    }
}

// ---------------------------------------------------------------------------
// Fused GEMM + LSE + writeout, v8: 16-row panels -> 1024 uniform blocks.
// Halved per-wave state (aF[4], acc[1]) targets VGPR<=~70 so 3-4 blocks/CU
// become RESIDENT (the 512-grid was the occupancy limiter, not VGPR).
// Swapped MFMA operands (round-14, verified): lane holds 4 consecutive m
// for one output row n = n0+c -> single float4 store, stats in 2 registers,
// wave-uniform tail masking (4000/2000 are multiples of 16).
// ---------------------------------------------------------------------------
__global__ __launch_bounds__(512, 4) void fused_kernel(
    const float* __restrict__ theta,
    const _Float16* __restrict__ B2T,
    const int* __restrict__ dom,
    float* __restrict__ out0, float* __restrict__ out1)
{
    __shared__ __align__(1024) char sA[16 * 256];   // 4 KB swizzled A panel
    __shared__ float smx[8][16];
    __shared__ float sms[8][16];
    __shared__ float slse[16];

    const int tid = threadIdx.x;
    const int w   = tid >> 6;     // 0..7
    const int ll  = tid & 63;
    const int g   = ll >> 4;      // 0..3
    const int c   = ll & 15;      // 0..15
    const int n0  = blockIdx.x * 16;

    // ---- stage A: theta f32 -> f16 + one-hot domain at k=100..103 ----
    if (tid < 256) {
        int row  = tid >> 4;          // 0..15
        int slot = tid & 15;
        const float* tr = theta + (size_t)(n0 + row) * PZ + slot * 8;
        half8v h = (half8v)(_Float16)0.f;
        if (slot < 12) {
            float4 lo = *(const float4*)tr;
            float4 hi = *(const float4*)(tr + 4);
            h[0] = (_Float16)lo.x; h[1] = (_Float16)lo.y;
            h[2] = (_Float16)lo.z; h[3] = (_Float16)lo.w;
            h[4] = (_Float16)hi.x; h[5] = (_Float16)hi.y;
            h[6] = (_Float16)hi.z; h[7] = (_Float16)hi.w;
        } else if (slot == 12) {
            float4 lo = *(const float4*)tr;   // k = 96..99
            h[0] = (_Float16)lo.x; h[1] = (_Float16)lo.y;
            h[2] = (_Float16)lo.z; h[3] = (_Float16)lo.w;
            int d = dom[n0 + row];            // k=100..103: one-hot(dom)
            h[4] = (_Float16)(d == 0 ? 1.f : 0.f);
            h[5] = (_Float16)(d == 1 ? 1.f : 0.f);
            h[6] = (_Float16)(d == 2 ? 1.f : 0.f);
            h[7] = (_Float16)(d == 3 ? 1.f : 0.f);
        }
        *(half8v*)(sA + row * 256 + ((slot ^ (row & 7)) * 16)) = h;
    }
    __syncthreads();

    // ---- A fragment (rows n0..n0+15) -> registers; row index = c ----
    half8v aF[4];
    #pragma unroll
    for (int kb = 0; kb < 4; ++kb) {
        int slot = (kb * 4 + g) ^ (c & 7);
        aF[kb] = *(const half8v*)(sA + c * 256 + slot * 16);
    }

    const int mwave = w * 16 + 4 * g;     // lane's first m within a tile

    for (int seg = 0; seg < 2; ++seg) {
        const int Mse = seg ? PM1 : PM0;
        const int NT  = seg ? 16 : 32;    // 128-col tiles (even)
        const _Float16* Bseg = B2T + (size_t)(seg ? SEG1ROW : 0) * KP;
        float* out = seg ? out1 : out0;

        const _Float16* bp0 = Bseg + (size_t)(w * 16 + c) * KP;  // lane's B row
        const size_t TSTEP = (size_t)128 * KP;

        float mx_ = -3.0e38f, sm_ = 0.f;

        auto loadB = [&](half8v (&bf)[4], const _Float16* p) {
            #pragma unroll
            for (int kb = 0; kb < 4; ++kb)
                bf[kb] = *(const half8v*)(p + kb * 32 + g * 8);
        };
        // swapped: bf is the A-operand -> D rows = m, D cols = n
        auto mfma4 = [&](half8v (&bf)[4], floatx4& a0) {
            a0 = (floatx4){0.f, 0.f, 0.f, 0.f};
            #pragma unroll
            for (int kb = 0; kb < 4; ++kb)
                a0 = __builtin_amdgcn_mfma_f32_16x16x32_f16(bf[kb], aF[kb], a0, 0, 0, 0);
        };
        auto stats_step = [&](floatx4& a0, int t) {
            if (t * 128 + w * 16 < Mse) {          // wave-uniform validity
                float tm = fmaxf(fmaxf(a0[0], a0[1]), fmaxf(a0[2], a0[3]));
                if (__all(tm - mx_ <= 8.0f)) {
                    sm_ += __expf(a0[0] - mx_) + __expf(a0[1] - mx_)
                         + __expf(a0[2] - mx_) + __expf(a0[3] - mx_);
                } else {
                    float nm = fmaxf(mx_, tm);
                    sm_ = sm_ * __expf(mx_ - nm)
                        + __expf(a0[0] - nm) + __expf(a0[1] - nm)
                        + __expf(a0[2] - nm) + __expf(a0[3] - nm);
                    mx_ = nm;
                }
            }
        };

        // =========== stats sweep, x2-unrolled prefetch ===========
        {
            half8v bA[4], bB[4];
            floatx4 a0;
            const _Float16* bp = bp0;
            loadB(bA, bp);
            for (int t = 0; t < NT; t += 2) {
                loadB(bB, bp + TSTEP);
                mfma4(bA, a0);
                stats_step(a0, t);
                if (t + 2 < NT) loadB(bA, bp + 2 * TSTEP);
                mfma4(bB, a0);
                stats_step(a0, t + 1);
                bp += 2 * TSTEP;
            }
        }

        // =========== reduce (g via shfl, waves via LDS) -> per-row LSE ======
        {
            float m_ = mx_, s_ = sm_;
            #pragma unroll
            for (int msk = 16; msk <= 32; msk <<= 1) {
                float mo = __shfl_xor(m_, msk), so = __shfl_xor(s_, msk);
                float nm = fmaxf(m_, mo);
                s_ = s_ * __expf(m_ - nm) + so * __expf(mo - nm);
                m_ = nm;
            }
            if (ll < 16) { smx[w][ll] = m_; sms[w][ll] = s_; }
        }
        __syncthreads();
        if (tid < 16) {
            float m_ = smx[0][tid], s_ = sms[0][tid];
            #pragma unroll
            for (int wv = 1; wv < 8; ++wv) {
                float mo = smx[wv][tid];
                float so = sms[wv][tid];
                float nm = fmaxf(m_, mo);
                s_ = s_ * __expf(m_ - nm) + so * __expf(mo - nm);
                m_ = nm;
            }
            slse[tid] = m_ + __logf(s_);
        }
        __syncthreads();
        const float lse = slse[c];
        __syncthreads();   // all reads done before next seg rewrites smx/slse

        // =========== write sweep (recompute), float4 plain stores ===========
        {
            float* p0 = out + (size_t)(n0 + c) * Mse + mwave;

            auto write_step = [&](floatx4& a0, int t) {
                if (t * 128 + w * 16 < Mse) {      // wave-uniform validity
                    floatx4 o0 = {a0[0] - lse, a0[1] - lse,
                                  a0[2] - lse, a0[3] - lse};
                    *(floatx4*)p0 = o0;
                }
                p0 += 128;
            };

            half8v bA[4], bB[4];
            floatx4 a0;
            const _Float16* bp = bp0;
            loadB(bA, bp);
            for (int t = 0; t < NT; t += 2) {
                loadB(bB, bp + TSTEP);
                mfma4(bA, a0);
                write_step(a0, t);
                if (t + 2 < NT) loadB(bA, bp + 2 * TSTEP);
                mfma4(bB, a0);
                write_step(a0, t + 1);
                bp += 2 * TSTEP;
            }
        }
    }
}

// ---------------------------------------------------------------------------
extern "C" void kernel_launch(void* const* d_in, const int* in_sizes, int n_in,
                              void* d_out, int out_size, void* d_ws, size_t ws_size,
                              hipStream_t stream) {
    const float* theta  = (const float*)d_in[0];
    const float* alpha0 = (const float*)d_in[1];
    const float* alpha1 = (const float*)d_in[2];
    const float* beta   = (const float*)d_in[3];
    const float* bias0  = (const float*)d_in[4];
    const float* bias1  = (const float*)d_in[5];
    const int*   dom    = (const int*)d_in[6];

    float* out0 = (float*)d_out;
    float* out1 = out0 + (size_t)PN * PM0;

    _Float16* B2T = (_Float16*)d_ws;   // [MROWS][KP] f16, 1.57 MB

    // 1. zero B2T (pads + unused k deterministically zero)
    {
        int n16 = MROWS * KP * 2 / 16;
        fill_kernel<<<(n16 + 255) / 256, 256, 0, stream>>>((uint4v*)B2T, n16);
    }

    // 2. topics -> B2T k=0..99
    topic_kernel<<<dim3(96, 5), 256, 0, stream>>>(alpha0, alpha1, beta, B2T);

    // 3. bias cols k=100..103
    bias_kernel<<<MROWS / 256, 256, 0, stream>>>(bias0, bias1, B2T);

    // 4. fused GEMM(+bias) + LSE + writeout: 1024 uniform blocks, 16 rows
    fused_kernel<<<PN / 16, 512, 0, stream>>>(theta, B2T, dom, out0, out1);
}

// Round 16
// 338.452 us; speedup vs baseline: 1.2584x; 1.2584x over previous
//
#include <hip/hip_runtime.h>
#include <hip/hip_bf16.h>

// Problem constants
#define PN 16384
#define PZ 100
#define PE 400
#define PM0 4000
#define PM1 2000
#define KP 128            // packed K: [0,100)=theta/topic, [100,104)=onehot/bias, rest 0
#define SEG1ROW 4096      // B2T row base / logit col base of segment 1
#define MPAD 6144         // 4096 (seg0 pad) + 2048 (seg1 pad)

typedef __attribute__((ext_vector_type(8))) _Float16 half8v;
typedef __attribute__((ext_vector_type(4))) _Float16 half4v;
typedef __attribute__((ext_vector_type(4))) float floatx4;
typedef __attribute__((ext_vector_type(4))) unsigned int uint4v;

__device__ __forceinline__ void gload16(const void* g, void* l) {
    __builtin_amdgcn_global_load_lds(
        (const __attribute__((address_space(1))) void*)g,
        (__attribute__((address_space(3))) void*)l, 16, 0, 0);
}

// ---------------------------------------------------------------------------
// zero-fill B2T (pads + k-slop deterministically zero)
// ---------------------------------------------------------------------------
__global__ __launch_bounds__(256) void fill_kernel(uint4v* __restrict__ p, int n16)
{
    int i = blockIdx.x * 256 + threadIdx.x;
    if (i < n16) p[i] = (uint4v){0u, 0u, 0u, 0u};
}

// ---------------------------------------------------------------------------
// topic v5 (proven ~28us): grid (96,5); block = 64 m x 20 z; 1 m x 5 z/thread.
// ---------------------------------------------------------------------------
__global__ __launch_bounds__(256) void topic_kernel(
    const float* __restrict__ alpha0, const float* __restrict__ alpha1,
    const float* __restrict__ beta, _Float16* __restrict__ b2t)
{
    __shared__ float sAl[64][101];   // 25.9 KB
    __shared__ float sBt[20][100];   // 8 KB

    const int seg = (blockIdx.x >= 64);
    const int tile = seg ? (blockIdx.x - 64) : blockIdx.x;
    const float* alpha = seg ? alpha1 : alpha0;
    const int Mse = seg ? PM1 : PM0;
    const int rowbase = (seg ? SEG1ROW : 0) + tile * 64;
    const int m0 = tile * 64;

    const int tid = threadIdx.x;
    const int ml = tid & 63;
    const int zt = tid >> 6;
    const int z0 = blockIdx.y * 20;

    float acc[5] = {0.f, 0.f, 0.f, 0.f, 0.f};

    for (int ec = 0; ec < 4; ++ec) {
        #pragma unroll
        for (int l = 0; l < 25; ++l) {
            int idx = tid + l * 256;
            int mr = idx / 100;
            int e  = idx - mr * 100;
            int mm = m0 + mr;
            sAl[mr][e] = (mm < Mse) ? alpha[(size_t)mm * PE + ec * 100 + e] : 0.f;
        }
        for (int idx = tid; idx < 2000; idx += 256) {
            int zr = idx / 100;
            int e  = idx - zr * 100;
            sBt[zr][e] = beta[(size_t)(z0 + zr) * PE + ec * 100 + e];
        }
        __syncthreads();

        #pragma unroll 2
        for (int e = 0; e < 100; ++e) {
            float a = sAl[ml][e];
            #pragma unroll
            for (int zi = 0; zi < 5; ++zi)
                acc[zi] = fmaf(sBt[zt * 5 + zi][e], a, acc[zi]);
        }
        __syncthreads();
    }

    int m = m0 + ml;
    if (m < Mse) {
        #pragma unroll
        for (int zi = 0; zi < 5; ++zi)
            b2t[(size_t)(rowbase + ml) * KP + (z0 + zt * 5 + zi)] = (_Float16)acc[zi];
    }
}

// ---------------------------------------------------------------------------
// bias cols k=100..103 of B2T (one thread per row)
// ---------------------------------------------------------------------------
__global__ __launch_bounds__(256) void bias_kernel(
    const float* __restrict__ bias0, const float* __restrict__ bias1,
    _Float16* __restrict__ b2t)
{
    int row = blockIdx.x * 256 + threadIdx.x;
    if (row >= MPAD) return;
    int seg = (row >= SEG1ROW);
    int m = row - (seg ? SEG1ROW : 0);
    int Mse = seg ? PM1 : PM0;
    const float* bias = seg ? bias1 : bias0;
    if (m < Mse) {
        #pragma unroll
        for (int d = 0; d < 4; ++d)
            b2t[(size_t)row * KP + 100 + d] = (_Float16)bias[(size_t)d * Mse + m];
    }
}

// ---------------------------------------------------------------------------
// GEMM: logit[n][mc] = f16( theta_f16[n][:] . B2T[mc][:] )  -- bias included
// via one-hot k=100..103. 128x128 tile, 4 waves (2x2), K=128 single-shot.
// Swapped MFMA operands: lane holds 4 consecutive m -> one half4 store/frag.
// ---------------------------------------------------------------------------
__global__ __launch_bounds__(256) void gemm_kernel(
    const float* __restrict__ theta,
    const _Float16* __restrict__ B2T,    // [MPAD][KP]
    const int* __restrict__ dom,
    _Float16* __restrict__ logit)        // [PN][MPAD]
{
    __shared__ __align__(1024) char sA[128 * 256];  // 32 KB, swizzled rows
    __shared__ __align__(1024) char sB[128 * 256];  // 32 KB

    const int tid = threadIdx.x;
    const int w   = tid >> 6;
    const int ll  = tid & 63;
    const int g   = ll >> 4;     // 0..3
    const int c   = ll & 15;     // 0..15
    const int wrow = (w & 1) * 64;      // n-offset of wave
    const int wcol = (w >> 1) * 64;     // m-offset of wave

    const int n0   = blockIdx.y * 128;
    const int mcol = blockIdx.x * 128;

    // ---- A stage: theta f32 -> f16 + one-hot(dom) at k=100..103 ----
    #pragma unroll
    for (int p = 0; p < 8; ++p) {
        int idx2 = tid + p * 256;        // 128 rows x 16 slots
        int row  = idx2 >> 4;
        int slot = idx2 & 15;
        const float* tr = theta + (size_t)(n0 + row) * PZ + slot * 8;
        half8v h = (half8v)(_Float16)0.f;
        if (slot < 12) {
            float4 lo = *(const float4*)tr;
            float4 hi = *(const float4*)(tr + 4);
            h[0] = (_Float16)lo.x; h[1] = (_Float16)lo.y;
            h[2] = (_Float16)lo.z; h[3] = (_Float16)lo.w;
            h[4] = (_Float16)hi.x; h[5] = (_Float16)hi.y;
            h[6] = (_Float16)hi.z; h[7] = (_Float16)hi.w;
        } else if (slot == 12) {
            float4 lo = *(const float4*)tr;   // k = 96..99
            h[0] = (_Float16)lo.x; h[1] = (_Float16)lo.y;
            h[2] = (_Float16)lo.z; h[3] = (_Float16)lo.w;
            int d = dom[n0 + row];            // k=100..103: one-hot(dom)
            h[4] = (_Float16)(d == 0 ? 1.f : 0.f);
            h[5] = (_Float16)(d == 1 ? 1.f : 0.f);
            h[6] = (_Float16)(d == 2 ? 1.f : 0.f);
            h[7] = (_Float16)(d == 3 ? 1.f : 0.f);
        }
        *(half8v*)(sA + row * 256 + ((slot ^ (row & 7)) * 16)) = h;
    }

    // ---- B stage: swizzled global_load_lds (linear dest, preswz source) ----
    {
        const int srow  = ll >> 4;       // 0..3 rows per instr
        const int sslot = ll & 15;
        #pragma unroll
        for (int it = 0; it < 8; ++it) {
            int row  = w * 32 + it * 4 + srow;
            int slot = sslot ^ (row & 7);
            gload16(B2T + (size_t)(mcol + row) * KP + slot * 8,
                    sB + (size_t)(w * 32 + it * 4) * 256);
        }
    }
    __syncthreads();

    // ---- MFMA: K=128 in 4 kb-steps, swapped operands (D rows = m) ----
    floatx4 acc[4][4];                   // [nj][mi]
    #pragma unroll
    for (int i = 0; i < 4; ++i)
        #pragma unroll
        for (int j = 0; j < 4; ++j)
            acc[i][j] = (floatx4){0.f, 0.f, 0.f, 0.f};

    #pragma unroll
    for (int kb = 0; kb < 4; ++kb) {
        half8v aF[4], bF[4];
        #pragma unroll
        for (int mi = 0; mi < 4; ++mi) {
            int row = wrow + mi * 16 + c;
            int slot = (kb * 4 + g) ^ (row & 7);
            aF[mi] = *(const half8v*)(sA + row * 256 + slot * 16);
        }
        #pragma unroll
        for (int nj = 0; nj < 4; ++nj) {
            int row = wcol + nj * 16 + c;
            int slot = (kb * 4 + g) ^ (row & 7);
            bF[nj] = *(const half8v*)(sB + row * 256 + slot * 16);
        }
        #pragma unroll
        for (int nj = 0; nj < 4; ++nj)
            #pragma unroll
            for (int mi = 0; mi < 4; ++mi)
                acc[nj][mi] = __builtin_amdgcn_mfma_f32_16x16x32_f16(
                    bF[nj], aF[mi], acc[nj][mi], 0, 0, 0);
    }

    // ---- epilogue: lane (g,c) of frag (nj,mi): n = wrow+mi*16+c,
    //      m = wcol+nj*16+4g+i (4 consecutive) -> one half4 store ----
    #pragma unroll
    for (int mi = 0; mi < 4; ++mi) {
        _Float16* lp = logit + (size_t)(n0 + wrow + mi * 16 + c) * MPAD
                             + mcol + wcol + 4 * g;
        #pragma unroll
        for (int nj = 0; nj < 4; ++nj) {
            half4v hv = {(_Float16)acc[nj][mi][0], (_Float16)acc[nj][mi][1],
                         (_Float16)acc[nj][mi][2], (_Float16)acc[nj][mi][3]};
            *(half4v*)(lp + nj * 16) = hv;
        }
    }
}

// ---------------------------------------------------------------------------
// LSE + writeout (pure streaming): one wave per row, row in registers.
// out[n][m] = v[n][m] - LSE_m(v),  v = stored f16 (logit+bias)
// ---------------------------------------------------------------------------
template<int NCH>
__global__ __launch_bounds__(256) void lsewrite_kernel(
    const _Float16* __restrict__ logit,   // [PN][MPAD]
    float* __restrict__ out, int M, int colOff)
{
    const int lane = threadIdx.x & 63;
    const int wv = threadIdx.x >> 6;
    const int n = blockIdx.x * 4 + wv;

    const _Float16* lp = logit + (size_t)n * MPAD + colOff;
    float* op = out + (size_t)n * M;

    float v[NCH][8];
    float mx = -3.0e38f;

    #pragma unroll
    for (int ci = 0; ci < NCH; ++ci) {
        int base = ci * 512 + lane * 8;
        if (base < M) {
            half8v hv = *(const half8v*)&lp[base];
            #pragma unroll
            for (int j = 0; j < 8; ++j) {
                v[ci][j] = (float)hv[j];
                mx = fmaxf(mx, v[ci][j]);
            }
        } else {
            #pragma unroll
            for (int j = 0; j < 8; ++j)
                v[ci][j] = -3.0e38f;
        }
    }

    #pragma unroll
    for (int off = 1; off < 64; off <<= 1)
        mx = fmaxf(mx, __shfl_xor(mx, off));

    float s = 0.f;
    #pragma unroll
    for (int ci = 0; ci < NCH; ++ci)
        #pragma unroll
        for (int j = 0; j < 8; ++j)
            s += __expf(v[ci][j] - mx);   // masked: exp(-inf) = 0

    #pragma unroll
    for (int off = 1; off < 64; off <<= 1)
        s += __shfl_xor(s, off);

    const float lse = mx + __logf(s);

    #pragma unroll
    for (int ci = 0; ci < NCH; ++ci) {
        int base = ci * 512 + lane * 8;
        if (base < M) {
            floatx4 o0 = {v[ci][0] - lse, v[ci][1] - lse,
                          v[ci][2] - lse, v[ci][3] - lse};
            floatx4 o1 = {v[ci][4] - lse, v[ci][5] - lse,
                          v[ci][6] - lse, v[ci][7] - lse};
            __builtin_nontemporal_store(o0, (floatx4*)&op[base]);
            __builtin_nontemporal_store(o1, (floatx4*)&op[base + 4]);
        }
    }
}

// ---------------------------------------------------------------------------
extern "C" void kernel_launch(void* const* d_in, const int* in_sizes, int n_in,
                              void* d_out, int out_size, void* d_ws, size_t ws_size,
                              hipStream_t stream) {
    const float* theta  = (const float*)d_in[0];
    const float* alpha0 = (const float*)d_in[1];
    const float* alpha1 = (const float*)d_in[2];
    const float* beta   = (const float*)d_in[3];
    const float* bias0  = (const float*)d_in[4];
    const float* bias1  = (const float*)d_in[5];
    const int*   dom    = (const int*)d_in[6];

    float* out0 = (float*)d_out;
    float* out1 = out0 + (size_t)PN * PM0;

    char* ws = (char*)d_ws;
    size_t off = 0;
    auto alloc = [&](size_t bytes) { char* p = ws + off; off = (off + bytes + 255) & ~(size_t)255; return p; };
    _Float16* B2T   = (_Float16*)alloc((size_t)MPAD * KP * 2);       // 1.57 MB
    _Float16* logit = (_Float16*)alloc((size_t)PN * MPAD * 2);       // 201 MB

    // 1. zero B2T (pads + unused k deterministically zero)
    {
        int n16 = MPAD * KP * 2 / 16;
        fill_kernel<<<(n16 + 255) / 256, 256, 0, stream>>>((uint4v*)B2T, n16);
    }

    // 2. topics -> B2T k=0..99
    topic_kernel<<<dim3(96, 5), 256, 0, stream>>>(alpha0, alpha1, beta, B2T);

    // 3. bias cols k=100..103
    bias_kernel<<<MPAD / 256, 256, 0, stream>>>(bias0, bias1, B2T);

    // 4. GEMM (+bias via one-hot) -> f16 logits, 6144 blocks
    gemm_kernel<<<dim3(MPAD / 128, PN / 128), 256, 0, stream>>>(
        theta, B2T, dom, logit);

    // 5. LSE + writeout per segment (one wave per row)
    lsewrite_kernel<8><<<PN / 4, 256, 0, stream>>>(logit, out0, PM0, 0);
    lsewrite_kernel<4><<<PN / 4, 256, 0, stream>>>(logit, out1, PM1, SEG1ROW);
}